// Round 2
// baseline (799.997 us; speedup 1.0000x reference)
//
#include <hip/hip_runtime.h>
#include <stdint.h>

#define TOKENS 4096
#define DMODEL 1024
#define DFF    4096
#define NEXP   8
#define NSLOTS (TOKENS*2)

typedef short  short8 __attribute__((ext_vector_type(8)));
typedef __bf16 bf16x8 __attribute__((ext_vector_type(8)));
typedef float  f32x4  __attribute__((ext_vector_type(4)));

__device__ __forceinline__ unsigned short f2bf(float f){
  unsigned int u = __float_as_uint(f);
  u += 0x7FFFu + ((u >> 16) & 1u);       // round-to-nearest-even
  return (unsigned short)(u >> 16);
}

__device__ __forceinline__ void gload16(const void* g, void* l){
  __builtin_amdgcn_global_load_lds((const __attribute__((address_space(1))) void*)g,
                                   (__attribute__((address_space(3))) void*)l, 16, 0, 0);
}

// ---------------- gate: logits fp32, top-2, softmax; also x -> bf16 ----------
__global__ __launch_bounds__(256) void gate_kernel(
    const float* __restrict__ x, const float* __restrict__ Wg, const float* __restrict__ bg,
    unsigned short* __restrict__ xbf, int* __restrict__ topi, float* __restrict__ topg,
    int* __restrict__ counts)
{
  int lane = threadIdx.x & 63;
  int t = blockIdx.x * 4 + (threadIdx.x >> 6);
  const float* xr = x + (size_t)t * DMODEL;
  float acc[8];
  #pragma unroll
  for (int e = 0; e < 8; e++) acc[e] = 0.f;
  float xv[16];
  #pragma unroll
  for (int j = 0; j < 16; j++) xv[j] = xr[lane + 64*j];
  #pragma unroll
  for (int j = 0; j < 16; j++){
    const float4* w = (const float4*)(Wg + (size_t)(lane + 64*j) * 8);
    float4 w0 = w[0], w1 = w[1];
    acc[0] += xv[j]*w0.x; acc[1] += xv[j]*w0.y;
    acc[2] += xv[j]*w0.z; acc[3] += xv[j]*w0.w;
    acc[4] += xv[j]*w1.x; acc[5] += xv[j]*w1.y;
    acc[6] += xv[j]*w1.z; acc[7] += xv[j]*w1.w;
  }
  #pragma unroll
  for (int e = 0; e < 8; e++){
    #pragma unroll
    for (int off = 32; off; off >>= 1) acc[e] += __shfl_xor(acc[e], off);
  }
  unsigned short* xo = xbf + (size_t)t * DMODEL;
  #pragma unroll
  for (int j = 0; j < 16; j++) xo[lane + 64*j] = f2bf(xv[j]);

  if (lane == 0){
    float v0 = -1e30f, v1 = -1e30f; int i0 = 0, i1 = 0;
    #pragma unroll
    for (int e = 0; e < 8; e++){
      float v = acc[e] + bg[e];
      if (v > v0){ v1 = v0; i1 = i0; v0 = v; i0 = e; }
      else if (v > v1){ v1 = v; i1 = e; }
    }
    float e1  = expf(v1 - v0);
    float inv = 1.f / (1.f + e1);
    topi[2*t]   = i0; topi[2*t+1] = i1;
    topg[2*t]   = inv; topg[2*t+1] = e1 * inv;
    atomicAdd(&counts[i0], 1); atomicAdd(&counts[i1], 1);
  }
}

__global__ void scan_kernel(const int* __restrict__ counts, int* __restrict__ base){
  if (threadIdx.x == 0 && blockIdx.x == 0){
    int s = 0;
    for (int e = 0; e < NEXP; e++){ base[e] = s; s += counts[e]; }
  }
}

__global__ __launch_bounds__(256) void route_kernel(
    const int* __restrict__ topi, const float* __restrict__ topg,
    const int* __restrict__ base, int* __restrict__ fill,
    int* __restrict__ slot_token, float* __restrict__ slot_gate)
{
  int t = blockIdx.x * 256 + threadIdx.x;
  if (t >= TOKENS) return;
  #pragma unroll
  for (int k = 0; k < 2; k++){
    int e = topi[2*t+k];
    int pos = atomicAdd(&fill[e], 1);
    int slot = base[e] + pos;
    slot_token[slot] = t;
    slot_gate[slot]  = topg[2*t+k];
  }
}

// ------------- transpose+convert: fp32 [E][R][C] -> bf16 [E][C][R] -----------
__global__ __launch_bounds__(256) void transpose_kernel(
    const float* __restrict__ in, unsigned short* __restrict__ out, int R, int C)
{
  __shared__ unsigned short tile[64][68];
  int cb = blockIdx.x * 64, rb = blockIdx.y * 64;
  size_t eoff = (size_t)blockIdx.z * R * C;
  const float* ip = in + eoff;
  unsigned short* op = out + eoff;
  int i  = threadIdx.x;
  int rr = i >> 4;
  int cc = (i & 15) * 4;
  #pragma unroll
  for (int j = 0; j < 4; j++){
    int r = j*16 + rr;
    float4 v = *(const float4*)(ip + (size_t)(rb + r) * C + cb + cc);
    tile[r][cc+0] = f2bf(v.x); tile[r][cc+1] = f2bf(v.y);
    tile[r][cc+2] = f2bf(v.z); tile[r][cc+3] = f2bf(v.w);
  }
  __syncthreads();
  #pragma unroll
  for (int j = 0; j < 4; j++){
    int c = j*16 + rr;
    ushort4 o;
    o.x = tile[cc+0][c]; o.y = tile[cc+1][c];
    o.z = tile[cc+2][c]; o.w = tile[cc+3][c];
    *(ushort4*)(op + (size_t)(cb + c) * R + rb + cc) = o;
  }
}

// ---------------- grouped GEMM: 128x128x32 tile, 4 waves, bf16 MFMA ----------
// MODE 0: h = gelu(x[token] @ W1[e] + b1[e])  -> Hout (bf16)
// MODE 1: out[token] += gate * (h[slot] @ W2[e] + b2[e])  (atomic fp32)
template<int KDIM, int NDIM, int MODE>
__global__ __launch_bounds__(256, 2) void moe_gemm(
    const unsigned short* __restrict__ A,
    const unsigned short* __restrict__ BT,     // [E][NDIM][KDIM] bf16 (K-contig)
    const float* __restrict__ bias,            // [E][NDIM]
    const int* __restrict__ slot_token,
    const float* __restrict__ slot_gate,
    const int* __restrict__ counts,
    const int* __restrict__ base,
    unsigned short* __restrict__ Hout,
    float* __restrict__ Out)
{
  int e  = blockIdx.y >> 5;
  int rt = blockIdx.y & 31;
  int rows = counts[e];
  if (rt * 128 >= rows) return;
  int sbase = base[e];

  __shared__ __align__(16) char smem[16384];
  char* As = smem;
  char* Bs = smem + 8192;

  int tid = threadIdx.x;
  int lane = tid & 63, wv = tid >> 6;

  // staging sources: flat slot f = p*256+tid; row=f>>2; phys j=f&3 holds logical
  // k-group g = j ^ ((row>>1)&3)  (pre-swizzled source, linear LDS dest)
  const char* asrc[2]; const char* bsrc[2];
  #pragma unroll
  for (int p = 0; p < 2; p++){
    int flat = p*256 + tid;
    int row  = flat >> 2;
    int g    = (flat & 3) ^ ((row >> 1) & 3);
    int r_use = min(rt*128 + row, rows - 1);
    int slot  = sbase + r_use;
    long arow = (MODE == 0) ? (long)slot_token[slot] : (long)slot;
    asrc[p] = (const char*)(A + (size_t)arow * KDIM) + g*16;
    size_t n = (size_t)blockIdx.x * 128 + row;
    bsrc[p] = (const char*)(BT + ((size_t)e * NDIM + n) * KDIM) + g*16;
  }

  int wr = wv >> 1, wc = wv & 1;
  int slotx = (lane >> 4) ^ ((lane >> 1) & 3);   // swizzled k-group slot per lane
  const char* Abase = As + (size_t)((wr*64 + (lane & 15)) * 64) + slotx*16;
  const char* Bbase = Bs + (size_t)((wc*64 + (lane & 15)) * 64) + slotx*16;

  f32x4 zero = {0.f, 0.f, 0.f, 0.f};
  f32x4 acc[4][4];
  #pragma unroll
  for (int m = 0; m < 4; m++)
    #pragma unroll
    for (int n = 0; n < 4; n++) acc[m][n] = zero;

  for (int k0 = 0; k0 < KDIM; k0 += 32){
    #pragma unroll
    for (int p = 0; p < 2; p++){
      gload16(asrc[p] + (size_t)k0*2, As + (p*256 + wv*64)*16);
      gload16(bsrc[p] + (size_t)k0*2, Bs + (p*256 + wv*64)*16);
    }
    __syncthreads();
    bf16x8 af[4], bfr[4];
    #pragma unroll
    for (int m = 0; m < 4; m++)
      af[m] = __builtin_bit_cast(bf16x8, *(const short8*)(Abase + m*1024));
    #pragma unroll
    for (int n = 0; n < 4; n++)
      bfr[n] = __builtin_bit_cast(bf16x8, *(const short8*)(Bbase + n*1024));
    #pragma unroll
    for (int m = 0; m < 4; m++)
      #pragma unroll
      for (int n = 0; n < 4; n++)
        acc[m][n] = __builtin_amdgcn_mfma_f32_16x16x32_bf16(af[m], bfr[n], acc[m][n], 0, 0, 0);
    __syncthreads();
  }

  int rlo = rt * 128;
  #pragma unroll
  for (int m = 0; m < 4; m++){
    int r_base = rlo + wr*64 + m*16 + ((lane >> 4) << 2);
    #pragma unroll
    for (int n = 0; n < 4; n++){
      int gcol = blockIdx.x*128 + wc*64 + n*16 + (lane & 15);
      float b = bias[e * NDIM + gcol];
      #pragma unroll
      for (int q = 0; q < 4; q++){
        int grow = r_base + q;
        if (grow < rows){
          float v = acc[m][n][q] + b;
          if (MODE == 0){
            float u  = v * (0.7978845608028654f + 0.0356774081f * v * v);
            float th = tanhf(u);
            float gel = 0.5f * v * (1.f + th);
            Hout[(size_t)(sbase + grow) * NDIM + gcol] = f2bf(gel);
          } else {
            int slot = sbase + grow;
            float gsc = slot_gate[slot];
            int tok   = slot_token[slot];
            atomicAdd(&Out[(size_t)tok * DMODEL + gcol], gsc * v);
          }
        }
      }
    }
  }
}

extern "C" void kernel_launch(void* const* d_in, const int* in_sizes, int n_in,
                              void* d_out, int out_size, void* d_ws, size_t ws_size,
                              hipStream_t stream)
{
  const float* x  = (const float*)d_in[0];
  const float* Wg = (const float*)d_in[1];
  const float* bg = (const float*)d_in[2];
  const float* W1 = (const float*)d_in[3];
  const float* b1 = (const float*)d_in[4];
  const float* W2 = (const float*)d_in[5];
  const float* b2 = (const float*)d_in[6];
  float* out = (float*)d_out;

  char* ws = (char*)d_ws;
  unsigned short* W1T = (unsigned short*)(ws);                               // 64MB
  unsigned short* W2T = (unsigned short*)(ws + (size_t)64*1024*1024);        // 64MB
  unsigned short* h   = (unsigned short*)(ws + (size_t)128*1024*1024);       // 64MB
  unsigned short* xbf = (unsigned short*)(ws + (size_t)192*1024*1024);       // 8MB
  char* meta = ws + (size_t)200*1024*1024;
  int*   slot_token = (int*)(meta);
  float* slot_gate  = (float*)(meta + 65536);
  int*   topi       = (int*)(meta + 131072);
  float* topg       = (float*)(meta + 196608);
  int*   counts     = (int*)(meta + 262144);
  int*   fill       = counts + 8;
  int*   base       = counts + 16;

  hipMemsetAsync(counts, 0, 96, stream);
  hipMemsetAsync(d_out, 0, (size_t)out_size * sizeof(float), stream);

  gate_kernel<<<TOKENS/4, 256, 0, stream>>>(x, Wg, bg, xbf, topi, topg, counts);
  scan_kernel<<<1, 64, 0, stream>>>(counts, base);
  route_kernel<<<TOKENS/256, 256, 0, stream>>>(topi, topg, base, fill, slot_token, slot_gate);
  transpose_kernel<<<dim3(DFF/64, DMODEL/64, NEXP), 256, 0, stream>>>(W1, W1T, DMODEL, DFF);
  transpose_kernel<<<dim3(DMODEL/64, DFF/64, NEXP), 256, 0, stream>>>(W2, W2T, DFF, DMODEL);
  moe_gemm<DMODEL, DFF, 0><<<dim3(DFF/128, NEXP*32), 256, 0, stream>>>(
      xbf, W1T, b1, slot_token, slot_gate, counts, base, h, (float*)nullptr);
  moe_gemm<DFF, DMODEL, 1><<<dim3(DMODEL/128, NEXP*32), 256, 0, stream>>>(
      h, W2T, b2, slot_token, slot_gate, counts, base, (unsigned short*)nullptr, out);
}

// Round 3
// 797.520 us; speedup vs baseline: 1.0031x; 1.0031x over previous
//
#include <hip/hip_runtime.h>
#include <stdint.h>

#define TOKENS 4096
#define DMODEL 1024
#define DFF    4096
#define NEXP   8
#define ROWT   16   // row tiles of 128 per expert: covers 2048 rows (mean 1024, sigma~30)

typedef short  short8 __attribute__((ext_vector_type(8)));
typedef __bf16 bf16x8 __attribute__((ext_vector_type(8)));
typedef float  f32x4  __attribute__((ext_vector_type(4)));

__device__ __forceinline__ unsigned short f2bf(float f){
  unsigned int u = __float_as_uint(f);
  u += 0x7FFFu + ((u >> 16) & 1u);       // round-to-nearest-even
  return (unsigned short)(u >> 16);
}

__device__ __forceinline__ void gload16(const void* g, void* l){
  __builtin_amdgcn_global_load_lds((const __attribute__((address_space(1))) void*)g,
                                   (__attribute__((address_space(3))) void*)l, 16, 0, 0);
}

// ---------------- gate: logits fp32, top-2, softmax; also x -> bf16 ----------
__global__ __launch_bounds__(256) void gate_kernel(
    const float* __restrict__ x, const float* __restrict__ Wg, const float* __restrict__ bg,
    unsigned short* __restrict__ xbf, int* __restrict__ topi, float* __restrict__ topg,
    int* __restrict__ counts)
{
  int lane = threadIdx.x & 63;
  int t = blockIdx.x * 4 + (threadIdx.x >> 6);
  const float* xr = x + (size_t)t * DMODEL;
  float acc[8];
  #pragma unroll
  for (int e = 0; e < 8; e++) acc[e] = 0.f;
  float xv[16];
  #pragma unroll
  for (int j = 0; j < 16; j++) xv[j] = xr[lane + 64*j];
  #pragma unroll
  for (int j = 0; j < 16; j++){
    const float4* w = (const float4*)(Wg + (size_t)(lane + 64*j) * 8);
    float4 w0 = w[0], w1 = w[1];
    acc[0] += xv[j]*w0.x; acc[1] += xv[j]*w0.y;
    acc[2] += xv[j]*w0.z; acc[3] += xv[j]*w0.w;
    acc[4] += xv[j]*w1.x; acc[5] += xv[j]*w1.y;
    acc[6] += xv[j]*w1.z; acc[7] += xv[j]*w1.w;
  }
  #pragma unroll
  for (int e = 0; e < 8; e++){
    #pragma unroll
    for (int off = 32; off; off >>= 1) acc[e] += __shfl_xor(acc[e], off);
  }
  unsigned short* xo = xbf + (size_t)t * DMODEL;
  #pragma unroll
  for (int j = 0; j < 16; j++) xo[lane + 64*j] = f2bf(xv[j]);

  if (lane == 0){
    float v0 = -1e30f, v1 = -1e30f; int i0 = 0, i1 = 0;
    #pragma unroll
    for (int e = 0; e < 8; e++){
      float v = acc[e] + bg[e];
      if (v > v0){ v1 = v0; i1 = i0; v0 = v; i0 = e; }
      else if (v > v1){ v1 = v; i1 = e; }
    }
    float e1  = expf(v1 - v0);
    float inv = 1.f / (1.f + e1);
    topi[2*t]   = i0; topi[2*t+1] = i1;
    topg[2*t]   = inv; topg[2*t+1] = e1 * inv;
    atomicAdd(&counts[i0], 1); atomicAdd(&counts[i1], 1);
  }
}

__global__ void scan_kernel(const int* __restrict__ counts, int* __restrict__ base){
  if (threadIdx.x == 0 && blockIdx.x == 0){
    int s = 0;
    for (int e = 0; e < NEXP; e++){ base[e] = s; s += counts[e]; }
  }
}

__global__ __launch_bounds__(256) void route_kernel(
    const int* __restrict__ topi, const float* __restrict__ topg,
    const int* __restrict__ base, int* __restrict__ fill,
    int* __restrict__ slot_token, float* __restrict__ slot_gate)
{
  int t = blockIdx.x * 256 + threadIdx.x;
  if (t >= TOKENS) return;
  #pragma unroll
  for (int k = 0; k < 2; k++){
    int e = topi[2*t+k];
    int pos = atomicAdd(&fill[e], 1);
    int slot = base[e] + pos;
    slot_token[slot] = t;
    slot_gate[slot]  = topg[2*t+k];
  }
}

// ------- transpose+convert: fp32 [E][R][C] -> bf16 [E][C][R], XOR-swizzled ---
// LDS: uint [64 rows][32 packed cols], phys col p = c2 ^ (r&31)  (2-way = free)
__global__ __launch_bounds__(256) void transpose_kernel(
    const float* __restrict__ in, unsigned short* __restrict__ out, int R, int C)
{
  __shared__ uint32_t lds[64 * 32];
  int cb = blockIdx.x * 64, rb = blockIdx.y * 64;
  size_t eoff = (size_t)blockIdx.z * R * C;
  const float* ip = in + eoff;
  unsigned short* op = out + eoff;
  int i = threadIdx.x;

  int r  = i >> 2;            // 0..63 tile row
  int cg = (i & 3) * 16;      // float col offset: 0,16,32,48
  const float* src = ip + (size_t)(rb + r) * C + cb + cg;
  float vv[16];
  #pragma unroll
  for (int q = 0; q < 4; q++){
    float4 v = *(const float4*)(src + 4*q);
    vv[4*q+0] = v.x; vv[4*q+1] = v.y; vv[4*q+2] = v.z; vv[4*q+3] = v.w;
  }
  #pragma unroll
  for (int u = 0; u < 8; u++){
    uint32_t w = (uint32_t)f2bf(vv[2*u]) | ((uint32_t)f2bf(vv[2*u+1]) << 16);
    int c2 = (cg >> 1) + u;
    lds[r * 32 + (c2 ^ (r & 31))] = w;
  }
  __syncthreads();

  int oc  = i >> 2;           // 0..63 output row (= source col)
  int c2  = oc >> 1;
  int sel = (oc & 1) * 16;
  #pragma unroll
  for (int h = 0; h < 2; h++){
    int rbase = h * 32 + (i & 3) * 8;
    uint32_t o[4];
    #pragma unroll
    for (int j = 0; j < 4; j++){
      int ra = rbase + 2*j, rb2 = ra + 1;
      uint32_t wa = lds[ra  * 32 + (c2 ^ (ra  & 31))];
      uint32_t wb = lds[rb2 * 32 + (c2 ^ (rb2 & 31))];
      o[j] = ((wa >> sel) & 0xFFFFu) | (((wb >> sel) & 0xFFFFu) << 16);
    }
    *(uint4*)(op + (size_t)(cb + oc) * R + rb + rbase) = *(uint4*)o;
  }
}

// ------- grouped GEMM: 128x128x32 tile, 4 waves, bf16 MFMA, 2-phase dbuf -----
// MODE 0: h = gelu(x[token] @ W1[e] + b1[e])  -> Hout (bf16)
// MODE 1: out[token] += gate * (h[slot] @ W2[e] + b2[e])  (atomic fp32)
template<int KDIM, int NDIM, int MODE>
__global__ __launch_bounds__(256, 2) void moe_gemm(
    const unsigned short* __restrict__ A,
    const unsigned short* __restrict__ BT,     // [E][NDIM][KDIM] bf16 (K-contig)
    const float* __restrict__ bias,            // [E][NDIM]
    const int* __restrict__ slot_token,
    const float* __restrict__ slot_gate,
    const int* __restrict__ counts,
    const int* __restrict__ base,
    unsigned short* __restrict__ Hout,
    float* __restrict__ Out)
{
  int e  = blockIdx.y / ROWT;
  int rt = blockIdx.y % ROWT;
  int rows = counts[e];
  if (rt * 128 >= rows) return;
  int sbase = base[e];

  __shared__ __align__(16) char smem[32768];   // 2 buffers x (8KB A + 8KB B)

  int tid = threadIdx.x;
  int lane = tid & 63, wv = tid >> 6;

  // staging sources: flat slot f = p*256+tid; row=f>>2; phys j=f&3 holds logical
  // k-group g = j ^ ((row>>1)&3)  (pre-swizzled source, linear LDS dest)
  const char* asrc[2]; const char* bsrc[2];
  #pragma unroll
  for (int p = 0; p < 2; p++){
    int flat = p*256 + tid;
    int row  = flat >> 2;
    int g    = (flat & 3) ^ ((row >> 1) & 3);
    int r_use = min(rt*128 + row, rows - 1);
    int slot  = sbase + r_use;
    long arow = (MODE == 0) ? (long)slot_token[slot] : (long)slot;
    asrc[p] = (const char*)(A + (size_t)arow * KDIM) + g*16;
    size_t n = (size_t)blockIdx.x * 128 + row;
    bsrc[p] = (const char*)(BT + ((size_t)e * NDIM + n) * KDIM) + g*16;
  }

  auto stage = [&](int buf, int k0){
    char* As = smem + buf*16384;
    char* Bs = As + 8192;
    #pragma unroll
    for (int p = 0; p < 2; p++){
      gload16(asrc[p] + (size_t)k0*2, As + (p*256 + wv*64)*16);
      gload16(bsrc[p] + (size_t)k0*2, Bs + (p*256 + wv*64)*16);
    }
  };

  int wr = wv >> 1, wc = wv & 1;
  int slotx = (lane >> 4) ^ ((lane >> 1) & 3);   // swizzled k-group slot per lane
  size_t aoff = (size_t)((wr*64 + (lane & 15)) * 64) + slotx*16;
  size_t boff = (size_t)((wc*64 + (lane & 15)) * 64) + slotx*16 + 8192;

  f32x4 zero = {0.f, 0.f, 0.f, 0.f};
  f32x4 acc[4][4];
  #pragma unroll
  for (int m = 0; m < 4; m++)
    #pragma unroll
    for (int n = 0; n < 4; n++) acc[m][n] = zero;

  stage(0, 0);
  __syncthreads();                 // compiler drains vmcnt(0) before barrier

  const int nt = KDIM / 32;
  int cur = 0;
  for (int t = 0; t < nt; ++t){
    if (t + 1 < nt) stage(cur ^ 1, (t + 1) * 32);   // prefetch in flight during compute
    const char* Ab = smem + cur*16384 + aoff;
    const char* Bb = smem + cur*16384 + boff;
    bf16x8 af[4], bfr[4];
    #pragma unroll
    for (int m = 0; m < 4; m++)
      af[m] = __builtin_bit_cast(bf16x8, *(const short8*)(Ab + m*1024));
    #pragma unroll
    for (int n = 0; n < 4; n++)
      bfr[n] = __builtin_bit_cast(bf16x8, *(const short8*)(Bb + n*1024));
    #pragma unroll
    for (int m = 0; m < 4; m++)
      #pragma unroll
      for (int n = 0; n < 4; n++)
        acc[m][n] = __builtin_amdgcn_mfma_f32_16x16x32_bf16(af[m], bfr[n], acc[m][n], 0, 0, 0);
    __syncthreads();               // drains vmcnt(0): prefetched tile resident
    cur ^= 1;
  }

  int rlo = rt * 128;
  #pragma unroll
  for (int m = 0; m < 4; m++){
    int r_base = rlo + wr*64 + m*16 + ((lane >> 4) << 2);
    #pragma unroll
    for (int n = 0; n < 4; n++){
      int gcol = blockIdx.x*128 + wc*64 + n*16 + (lane & 15);
      float b = bias[e * NDIM + gcol];
      #pragma unroll
      for (int q = 0; q < 4; q++){
        int grow = r_base + q;
        if (grow < rows){
          float v = acc[m][n][q] + b;
          if (MODE == 0){
            float u  = v * (0.7978845608028654f + 0.0356774081f * v * v);
            float th = tanhf(u);
            float gel = 0.5f * v * (1.f + th);
            Hout[(size_t)(sbase + grow) * NDIM + gcol] = f2bf(gel);
          } else {
            int slot = sbase + grow;
            float gsc = slot_gate[slot];
            int tok   = slot_token[slot];
            atomicAdd(&Out[(size_t)tok * DMODEL + gcol], gsc * v);
          }
        }
      }
    }
  }
}

extern "C" void kernel_launch(void* const* d_in, const int* in_sizes, int n_in,
                              void* d_out, int out_size, void* d_ws, size_t ws_size,
                              hipStream_t stream)
{
  const float* x  = (const float*)d_in[0];
  const float* Wg = (const float*)d_in[1];
  const float* bg = (const float*)d_in[2];
  const float* W1 = (const float*)d_in[3];
  const float* b1 = (const float*)d_in[4];
  const float* W2 = (const float*)d_in[5];
  const float* b2 = (const float*)d_in[6];
  float* out = (float*)d_out;

  char* ws = (char*)d_ws;
  unsigned short* W1T = (unsigned short*)(ws);                               // 64MB
  unsigned short* W2T = (unsigned short*)(ws + (size_t)64*1024*1024);        // 64MB
  unsigned short* h   = (unsigned short*)(ws + (size_t)128*1024*1024);       // 64MB
  unsigned short* xbf = (unsigned short*)(ws + (size_t)192*1024*1024);       // 8MB
  char* meta = ws + (size_t)200*1024*1024;
  int*   slot_token = (int*)(meta);
  float* slot_gate  = (float*)(meta + 65536);
  int*   topi       = (int*)(meta + 131072);
  float* topg       = (float*)(meta + 196608);
  int*   counts     = (int*)(meta + 262144);
  int*   fill       = counts + 8;
  int*   base       = counts + 16;

  hipMemsetAsync(counts, 0, 96, stream);
  hipMemsetAsync(d_out, 0, (size_t)out_size * sizeof(float), stream);

  gate_kernel<<<TOKENS/4, 256, 0, stream>>>(x, Wg, bg, xbf, topi, topg, counts);
  scan_kernel<<<1, 64, 0, stream>>>(counts, base);
  route_kernel<<<TOKENS/256, 256, 0, stream>>>(topi, topg, base, fill, slot_token, slot_gate);
  transpose_kernel<<<dim3(DFF/64, DMODEL/64, NEXP), 256, 0, stream>>>(W1, W1T, DMODEL, DFF);
  transpose_kernel<<<dim3(DMODEL/64, DFF/64, NEXP), 256, 0, stream>>>(W2, W2T, DFF, DMODEL);
  moe_gemm<DMODEL, DFF, 0><<<dim3(DFF/128, NEXP*ROWT), 256, 0, stream>>>(
      xbf, W1T, b1, slot_token, slot_gate, counts, base, h, (float*)nullptr);
  moe_gemm<DFF, DMODEL, 1><<<dim3(DMODEL/128, NEXP*ROWT), 256, 0, stream>>>(
      h, W2T, b2, slot_token, slot_gate, counts, base, (unsigned short*)nullptr, out);
}